// Round 3
// baseline (330.744 us; speedup 1.0000x reference)
//
#include <hip/hip_runtime.h>
#include <hip/hip_bf16.h>
#include <math.h>

#define B_    8
#define S_    8192
#define DIN_  512
#define DH_   512
#define HN_   4
#define HD_   128
#define CHUNK_ 16
#define NC_   (S_/CHUNK_)
#define NTOK  (B_*S_)

typedef __bf16 bf16x8 __attribute__((ext_vector_type(8)));
typedef float  f32x4  __attribute__((ext_vector_type(4)));

__device__ __forceinline__ float sigmoidf_(float z) { return 1.0f / (1.0f + expf(-z)); }

__device__ __forceinline__ unsigned short f2bf(float f) {
    union { float f; unsigned u; } v; v.f = f;
    unsigned u = v.u;
    u += 0x7fffu + ((u >> 16) & 1u);   // RNE
    return (unsigned short)(u >> 16);
}
__device__ __forceinline__ unsigned long long pack4bf(float4 a) {
    return (unsigned long long)f2bf(a.x)
         | ((unsigned long long)f2bf(a.y) << 16)
         | ((unsigned long long)f2bf(a.z) << 32)
         | ((unsigned long long)f2bf(a.w) << 48);
}
__device__ __forceinline__ void gload_lds16(const void* g, void* lds) {
    __builtin_amdgcn_global_load_lds(
        (const __attribute__((address_space(1))) unsigned int*)g,
        (__attribute__((address_space(3))) unsigned int*)lds, 16, 0, 0);
}

// ---------------------------------------------------------------------------
// k0: convert W_in / W_out f32 -> bf16, pre-permuted to LDS layout:
//   Wre[kt16][o][c][j] = W[c][kt16*32 + o*8 + j]
// ---------------------------------------------------------------------------
__global__ __launch_bounds__(256) void k0_convert(
    const float* __restrict__ Win, const float* __restrict__ Wout,
    unsigned short* __restrict__ WreA, unsigned short* __restrict__ WreB)
{
    int idx = blockIdx.x * 256 + threadIdx.x;
    if (idx < 262144) {
        int c = idx >> 9, k = idx & 511;
        int dst = ((k >> 5) << 14) + (((k >> 3) & 3) << 12) + (c << 3) + (k & 7);
        WreA[dst] = f2bf(Win[idx]);
        WreB[dst] = f2bf(Wout[idx]);
    }
}

// ---------------------------------------------------------------------------
// k1_fused: xp = x @ Win^T (bf16 MFMA, BM=64, 4 waves, acc[4][8]) then fused
// epilogue: LayerNorm -> gates -> b=beta*xn -> per-chunk cumprod p / clamped
// cumsum B0. Writes B0 (f32, d_out) + p_buf. Block owns 64 rows = 4 chunks.
// ---------------------------------------------------------------------------
__global__ __launch_bounds__(256) void k1_fused(
    const float* __restrict__ x, const unsigned short* __restrict__ Wre,
    const float* __restrict__ Wg, const float* __restrict__ bg,
    const float* __restrict__ gamma, const float* __restrict__ beta,
    const float* __restrict__ eig_raw,
    float* __restrict__ outB0, float* __restrict__ p_buf)
{
    // main-loop staging (36 KB), overlaid by epilogue scratch after the loop
    __shared__ alignas(16) char smem0[36864];
    unsigned short (*Blds)[512][8] = (unsigned short (*)[512][8])smem0;           // 32 KB
    unsigned short (*Alds)[64][8]  = (unsigned short (*)[64][8])(smem0 + 32768);  // 4 KB
    // epilogue overlays (valid only after post-loop __syncthreads)
    float* redS  = (float*)smem0;            // [4][64]
    float* redQ  = (float*)(smem0 + 1024);   // [4][64]
    float* redG  = (float*)(smem0 + 2048);   // [4][64][8]
    float* meanL = (float*)(smem0 + 10240);  // [64]
    float* rstdL = (float*)(smem0 + 10496);  // [64]
    float* qL    = (float*)(smem0 + 10752);  // [64][4]
    float* btgL  = (float*)(smem0 + 11776);  // [64][4]
    float* aL    = (float*)(smem0 + 12800);  // [64][4]
    __shared__ float WgL[8][512];            // 16 KB, persists whole kernel

    const int tid = threadIdx.x;
    const int l = tid & 63, wc = tid >> 6;
    const int og = l >> 4, lr = l & 15;
    const long t0 = (long)blockIdx.x * 64;

    // stage Wg (read in epilogue only; first loop barrier orders it)
    #pragma unroll
    for (int i = 0; i < 4; ++i)
        ((float4*)WgL)[tid + 256 * i] = ((const float4*)Wg)[tid + 256 * i];

    float gam[8], bet[8];
    #pragma unroll
    for (int n = 0; n < 8; ++n) {
        int c = (wc << 7) + (n << 4) + lr;
        gam[n] = gamma[c]; bet[n] = beta[c];
    }

    f32x4 acc[4][8];
    #pragma unroll
    for (int m = 0; m < 4; ++m)
        #pragma unroll
        for (int n = 0; n < 8; ++n) acc[m][n] = (f32x4)(0.f);

    for (int kt16 = 0; kt16 < 16; ++kt16) {
        const int kt = kt16 << 5;
        __syncthreads();
        // stage B: 32 KB direct-to-LDS
        const char* gW = (const char*)Wre + ((long)kt16 << 15);
        char* lB = (char*)smem0 + (wc << 10);
        #pragma unroll
        for (int i = 0; i < 8; ++i)
            gload_lds16(gW + (i << 12) + (wc << 10) + (l << 4), lB + (i << 12));
        // stage A: 64 rows x 32 k, 2 quads/thread
        #pragma unroll
        for (int s = 0; s < 2; ++s) {
            int slot = tid + (s << 8);
            int row = slot >> 3, q = slot & 7;
            float4 av = *(const float4*)&x[(t0 + row) * 512 + kt + (q << 2)];
            *reinterpret_cast<unsigned long long*>(&Alds[q >> 1][row][(q & 1) << 2]) = pack4bf(av);
        }
        __syncthreads();

        bf16x8 afr[4], bfr[8];
        #pragma unroll
        for (int m = 0; m < 4; ++m)
            afr[m] = *reinterpret_cast<const bf16x8*>(&Alds[og][(m << 4) + lr][0]);
        #pragma unroll
        for (int n = 0; n < 8; ++n)
            bfr[n] = *reinterpret_cast<const bf16x8*>(&Blds[og][(wc << 7) + (n << 4) + lr][0]);
        #pragma unroll
        for (int m = 0; m < 4; ++m)
            #pragma unroll
            for (int n = 0; n < 8; ++n)
                acc[m][n] = __builtin_amdgcn_mfma_f32_16x16x32_bf16(afr[m], bfr[n], acc[m][n], 0, 0, 0);
    }
    __syncthreads();   // staging LDS dead; epilogue overlays it

    // ---- LayerNorm reductions ----
    float s1v[4][4], s2v[4][4];
    #pragma unroll
    for (int m = 0; m < 4; ++m)
        #pragma unroll
        for (int j = 0; j < 4; ++j) {
            float s1 = 0.f, s2 = 0.f;
            #pragma unroll
            for (int n = 0; n < 8; ++n) { float v = acc[m][n][j]; s1 += v; s2 += v * v; }
            #pragma unroll
            for (int off = 1; off < 16; off <<= 1) {
                s1 += __shfl_xor(s1, off, 64);
                s2 += __shfl_xor(s2, off, 64);
            }
            s1v[m][j] = s1; s2v[m][j] = s2;
        }
    if (lr == 0) {
        #pragma unroll
        for (int m = 0; m < 4; ++m)
            #pragma unroll
            for (int j = 0; j < 4; ++j) {
                int r = (m << 4) + (og << 2) + j;
                redS[wc * 64 + r] = s1v[m][j];
                redQ[wc * 64 + r] = s2v[m][j];
            }
    }
    __syncthreads();
    if (tid < 64) {
        int r = tid;
        float S = redS[r] + redS[64 + r] + redS[128 + r] + redS[192 + r];
        float Q = redQ[r] + redQ[64 + r] + redQ[128 + r] + redQ[192 + r];
        float mean = S * (1.f / 512.f);
        float var  = Q * (1.f / 512.f) - mean * mean;
        meanL[r] = mean;
        rstdL[r] = 1.0f / sqrtf(var + 1e-5f);
    }
    __syncthreads();

    // ---- normalize in-register ----
    #pragma unroll
    for (int m = 0; m < 4; ++m)
        #pragma unroll
        for (int j = 0; j < 4; ++j) {
            int r = (m << 4) + (og << 2) + j;
            float mu = meanL[r], rs = rstdL[r];
            #pragma unroll
            for (int n = 0; n < 8; ++n)
                acc[m][n][j] = (acc[m][n][j] - mu) * rs * gam[n] + bet[n];
        }

    // ---- gate dots (f32) ----
    #pragma unroll
    for (int g = 0; g < 8; ++g) {
        float wgv[8];
        #pragma unroll
        for (int n = 0; n < 8; ++n) wgv[n] = WgL[g][(wc << 7) + (n << 4) + lr];
        #pragma unroll
        for (int m = 0; m < 4; ++m)
            #pragma unroll
            for (int j = 0; j < 4; ++j) {
                float p = 0.f;
                #pragma unroll
                for (int n = 0; n < 8; ++n) p = fmaf(acc[m][n][j], wgv[n], p);
                #pragma unroll
                for (int off = 1; off < 16; off <<= 1) p += __shfl_xor(p, off, 64);
                if (lr == 0) redG[(wc * 64 + (m << 4) + (og << 2) + j) * 8 + g] = p;
            }
    }
    __syncthreads();
    if (tid < 64) {
        int r = tid;
        #pragma unroll
        for (int n = 0; n < 4; ++n) {
            float ga = redG[r * 8 + n] + redG[(64 + r) * 8 + n]
                     + redG[(128 + r) * 8 + n] + redG[(192 + r) * 8 + n] + bg[n];
            float gb = redG[r * 8 + 4 + n] + redG[(64 + r) * 8 + 4 + n]
                     + redG[(128 + r) * 8 + 4 + n] + redG[(192 + r) * 8 + 4 + n] + bg[4 + n];
            aL[r * 4 + n]   = tanhf(eig_raw[n]) * sigmoidf_(ga);
            btgL[r * 4 + n] = sigmoidf_(gb);
        }
    }
    __syncthreads();
    // ---- per-chunk cumprod (4 chunks x 4 heads) ----
    if (tid < 16) {
        int cb = tid >> 2, n = tid & 3;
        float p = 1.f;
        for (int t = 0; t < 16; ++t) {
            int r = cb * 16 + t;
            p *= aL[r * 4 + n];
            p_buf[(t0 + r) * 4 + n] = p;
            qL[r * 4 + n] = fmaxf(p, 1e-6f);
        }
    }
    __syncthreads();

    // ---- B0 = q * cumsum(b/q) within chunk (chunk == m), write out ----
    #pragma unroll
    for (int m = 0; m < 4; ++m) {
        float qv[4], btv[4], rq[4];
        #pragma unroll
        for (int j = 0; j < 4; ++j) {
            int r = (m << 4) + (og << 2) + j;
            qv[j]  = qL[r * 4 + wc];
            btv[j] = btgL[r * 4 + wc];
            rq[j]  = 1.0f / qv[j];
        }
        #pragma unroll
        for (int n = 0; n < 8; ++n) {
            float v0 = btv[0] * acc[m][n][0] * rq[0];
            float v1 = v0 + btv[1] * acc[m][n][1] * rq[1];
            float v2 = v1 + btv[2] * acc[m][n][2] * rq[2];
            float v3 = v2 + btv[3] * acc[m][n][3] * rq[3];
            float T = v3, incl = T;
            float sh = __shfl(incl, (l + 48) & 63, 64); if (og >= 1) incl += sh;
            sh = __shfl(incl, (l + 32) & 63, 64);       if (og >= 2) incl += sh;
            float pre = incl - T;
            long base = (t0 + (m << 4) + (og << 2)) * 512 + (wc << 7) + (n << 4) + lr;
            outB0[base]        = qv[0] * (v0 + pre);
            outB0[base + 512]  = qv[1] * (v1 + pre);
            outB0[base + 1024] = qv[2] * (v2 + pre);
            outB0[base + 1536] = qv[3] * (v3 + pre);
        }
    }
}

// ---------------------------------------------------------------------------
// k3 (phase B): sequential scan over 512 chunk carries, 4096 parallel lanes.
// ---------------------------------------------------------------------------
__global__ __launch_bounds__(256) void k3_scan(
    const float* __restrict__ p_buf, const float* __restrict__ bvec,
    const float* __restrict__ h_in, float* __restrict__ h0_buf,
    float* __restrict__ h_last)
{
    const int tid = blockIdx.x * blockDim.x + threadIdx.x; // 0..4095
    const int b = tid >> 9, c = tid & 511, n = c >> 7;
    float h = h_in[b * DH_ + c];
    for (int ch = 0; ch < NC_; ++ch) {
        h0_buf[((long)(b * NC_ + ch)) * DH_ + c] = h;
        long sE = (long)b * S_ + (long)ch * CHUNK_ + (CHUNK_ - 1);
        float p15 = p_buf[sE * HN_ + n];
        float B15 = bvec[sE * DH_ + c];
        h = fmaf(p15, h, B15);
    }
    h_last[b * DH_ + c] = h;
}

// ---------------------------------------------------------------------------
// k5_fused: out = (B0 + p*h0) @ Wout^T, in place over d_out. BM=64, acc[4][8].
// Phase C fused into A-staging.
// ---------------------------------------------------------------------------
__global__ __launch_bounds__(256) void k5_fused(
    const unsigned short* __restrict__ Wre,
    const float* __restrict__ p_buf, const float* __restrict__ h0_buf,
    float* io)
{
    __shared__ alignas(16) unsigned short Blds[4][512][8];   // 32 KB
    __shared__ alignas(16) unsigned short Alds[4][64][8];    // 4 KB
    const int tid = threadIdx.x;
    const int l = tid & 63, wc = tid >> 6;
    const int og = l >> 4, lr = l & 15;
    const long t0 = (long)blockIdx.x * 64;

    f32x4 acc[4][8];
    #pragma unroll
    for (int m = 0; m < 4; ++m)
        #pragma unroll
        for (int n = 0; n < 8; ++n) acc[m][n] = (f32x4)(0.f);

    for (int kt16 = 0; kt16 < 16; ++kt16) {
        const int kt = kt16 << 5;
        __syncthreads();
        const char* gW = (const char*)Wre + ((long)kt16 << 15);
        char* lB = (char*)&Blds[0][0][0] + (wc << 10);
        #pragma unroll
        for (int i = 0; i < 8; ++i)
            gload_lds16(gW + (i << 12) + (wc << 10) + (l << 4), lB + (i << 12));
        #pragma unroll
        for (int s = 0; s < 2; ++s) {
            int slot = tid + (s << 8);
            int row = slot >> 3, q = slot & 7;
            long atok = t0 + row;
            int k0 = kt + (q << 2);
            float4 bv = *(const float4*)&io[atok * 512 + k0];
            float4 h0 = *(const float4*)&h0_buf[(atok >> 4) * 512 + k0];
            float p = p_buf[(atok << 2) + (k0 >> 7)];
            float4 av;
            av.x = fmaf(p, h0.x, bv.x);
            av.y = fmaf(p, h0.y, bv.y);
            av.z = fmaf(p, h0.z, bv.z);
            av.w = fmaf(p, h0.w, bv.w);
            *reinterpret_cast<unsigned long long*>(&Alds[q >> 1][row][(q & 1) << 2]) = pack4bf(av);
        }
        __syncthreads();

        bf16x8 afr[4], bfr[8];
        #pragma unroll
        for (int m = 0; m < 4; ++m)
            afr[m] = *reinterpret_cast<const bf16x8*>(&Alds[og][(m << 4) + lr][0]);
        #pragma unroll
        for (int n = 0; n < 8; ++n)
            bfr[n] = *reinterpret_cast<const bf16x8*>(&Blds[og][(wc << 7) + (n << 4) + lr][0]);
        #pragma unroll
        for (int m = 0; m < 4; ++m)
            #pragma unroll
            for (int n = 0; n < 8; ++n)
                acc[m][n] = __builtin_amdgcn_mfma_f32_16x16x32_bf16(afr[m], bfr[n], acc[m][n], 0, 0, 0);
    }

    #pragma unroll
    for (int m = 0; m < 4; ++m) {
        const long rb = t0 + (m << 4) + (og << 2);
        #pragma unroll
        for (int n = 0; n < 8; ++n) {
            const int col = (wc << 7) + (n << 4) + lr;
            #pragma unroll
            for (int j = 0; j < 4; ++j)
                io[(rb + j) * 512 + col] = acc[m][n][j];
        }
    }
}

extern "C" void kernel_launch(void* const* d_in, const int* in_sizes, int n_in,
                              void* d_out, int out_size, void* d_ws, size_t ws_size,
                              hipStream_t stream) {
    const float* x       = (const float*)d_in[0];
    const float* h       = (const float*)d_in[1];
    const float* Win     = (const float*)d_in[2];
    const float* gamma   = (const float*)d_in[3];
    const float* beta    = (const float*)d_in[4];
    const float* Wg      = (const float*)d_in[5];
    const float* bg      = (const float*)d_in[6];
    const float* eig_raw = (const float*)d_in[7];
    const float* Wout    = (const float*)d_in[8];

    float* out    = (float*)d_out;                // B0 -> (h_all fused) -> out
    float* h_last = out + (long)NTOK * DH_;

    float* ws     = (float*)d_ws;
    float* p_buf  = ws;                            // 262144 f
    float* h0_buf = ws + 262144;                   // 2097152 f
    unsigned short* WreA = (unsigned short*)(ws + 2359296);  // 262144 us
    unsigned short* WreB = WreA + 262144;                    // 262144 us

    k0_convert<<<1024, 256, 0, stream>>>(Win, Wout, WreA, WreB);
    k1_fused<<<NTOK/64, 256, 0, stream>>>(x, WreA, Wg, bg, gamma, beta, eig_raw,
                                          out, p_buf);
    k3_scan<<<16, 256, 0, stream>>>(p_buf, out, h, h0_buf, h_last);
    k5_fused<<<NTOK/64, 256, 0, stream>>>(WreB, p_buf, h0_buf, out);
}

// Round 4
// 327.413 us; speedup vs baseline: 1.0102x; 1.0102x over previous
//
#include <hip/hip_runtime.h>
#include <hip/hip_bf16.h>
#include <math.h>

#define B_    8
#define S_    8192
#define DIN_  512
#define DH_   512
#define HN_   4
#define HD_   128
#define CHUNK_ 16
#define NC_   (S_/CHUNK_)
#define NTOK  (B_*S_)

typedef __bf16 bf16x8 __attribute__((ext_vector_type(8)));
typedef float  f32x4  __attribute__((ext_vector_type(4)));

__device__ __forceinline__ float sigmoidf_(float z) { return 1.0f / (1.0f + expf(-z)); }

__device__ __forceinline__ unsigned short f2bf(float f) {
    union { float f; unsigned u; } v; v.f = f;
    unsigned u = v.u;
    u += 0x7fffu + ((u >> 16) & 1u);   // RNE
    return (unsigned short)(u >> 16);
}
__device__ __forceinline__ unsigned long long pack4bf(float4 a) {
    return (unsigned long long)f2bf(a.x)
         | ((unsigned long long)f2bf(a.y) << 16)
         | ((unsigned long long)f2bf(a.z) << 32)
         | ((unsigned long long)f2bf(a.w) << 48);
}
__device__ __forceinline__ void gload_lds16(const void* g, void* lds) {
    __builtin_amdgcn_global_load_lds(
        (const __attribute__((address_space(1))) unsigned int*)g,
        (__attribute__((address_space(3))) unsigned int*)lds, 16, 0, 0);
}

// ---------------------------------------------------------------------------
// k0: convert W_in / W_out f32 -> bf16, pre-permuted to LDS layout:
//   Wre[kt16][o][c][j] = W[c][kt16*32 + o*8 + j]
// ---------------------------------------------------------------------------
__global__ __launch_bounds__(256) void k0_convert(
    const float* __restrict__ Win, const float* __restrict__ Wout,
    unsigned short* __restrict__ WreA, unsigned short* __restrict__ WreB)
{
    int idx = blockIdx.x * 256 + threadIdx.x;
    if (idx < 262144) {
        int c = idx >> 9, k = idx & 511;
        int dst = ((k >> 5) << 14) + (((k >> 3) & 3) << 12) + (c << 3) + (k & 7);
        WreA[dst] = f2bf(Win[idx]);
        WreB[dst] = f2bf(Wout[idx]);
    }
}

// ---------------------------------------------------------------------------
// gemm_rows: out[t][c] = sum_k A[t][k]*W[c][k]. BM=32 (whole row N=512,
// in-place safe), 4 waves, acc[2][8] per wave. Double-buffered LDS (T3
// 2-phase): issue next tile's loads BEFORE current tile's MFMA; ONE barrier
// per K-step; __syncthreads' vmcnt(0) lands after MFMA hid the latency.
// FUSED: A[t][k] = bvec[t][k] + p[t,k>>7]*h0[t>>4][k]  (phase C on the fly)
// ---------------------------------------------------------------------------
template<bool FUSED>
__global__ __launch_bounds__(256) void gemm_rows(
    const float* Asrc,                          // aliases out when FUSED
    const unsigned short* __restrict__ Wre,
    const float* __restrict__ p_buf,
    const float* __restrict__ h0_buf,
    float* out)
{
    __shared__ alignas(16) unsigned short Blds[2][4][512][8];  // 64 KB
    __shared__ alignas(16) unsigned short Alds[2][4][32][8];   // 4 KB

    const int tid = threadIdx.x;
    const int l = tid & 63, wc = tid >> 6;
    const int og = l >> 4, lr = l & 15;
    const long t0 = (long)blockIdx.x * 32;
    const int arow = tid >> 3, aq = tid & 7;
    const long atok = t0 + arow;

    f32x4 acc[2][8];
    #pragma unroll
    for (int m = 0; m < 2; ++m)
        #pragma unroll
        for (int n = 0; n < 8; ++n) acc[m][n] = (f32x4)(0.f);

    float4 bv, h0; float pp;

    // ---- prologue: stage tile 0 into buf 0 ----
    {
        const char* gW = (const char*)Wre;
        char* lB = (char*)&Blds[0][0][0][0] + (wc << 10);
        #pragma unroll
        for (int i = 0; i < 8; ++i)
            gload_lds16(gW + (i << 12) + (wc << 10) + (l << 4), lB + (i << 12));
        const int k0 = aq << 2;
        bv = *(const float4*)&Asrc[atok * 512 + k0];
        if (FUSED) {
            h0 = *(const float4*)&h0_buf[(atok >> 4) * 512 + k0];
            pp = p_buf[(atok << 2) + (k0 >> 7)];
        }
        float4 av = bv;
        if (FUSED) {
            av.x = fmaf(pp, h0.x, bv.x); av.y = fmaf(pp, h0.y, bv.y);
            av.z = fmaf(pp, h0.z, bv.z); av.w = fmaf(pp, h0.w, bv.w);
        }
        *reinterpret_cast<unsigned long long*>(&Alds[0][aq >> 1][arow][(aq & 1) << 2]) = pack4bf(av);
    }
    __syncthreads();

    for (int kt16 = 0; kt16 < 16; ++kt16) {
        const int cur = kt16 & 1;
        // ---- issue next tile's loads (in flight across the MFMA phase) ----
        if (kt16 < 15) {
            const char* gW = (const char*)Wre + ((long)(kt16 + 1) << 15);
            char* lB = (char*)&Blds[cur ^ 1][0][0][0] + (wc << 10);
            #pragma unroll
            for (int i = 0; i < 8; ++i)
                gload_lds16(gW + (i << 12) + (wc << 10) + (l << 4), lB + (i << 12));
            const int k0 = ((kt16 + 1) << 5) + (aq << 2);
            bv = *(const float4*)&Asrc[atok * 512 + k0];
            if (FUSED) {
                h0 = *(const float4*)&h0_buf[(atok >> 4) * 512 + k0];
                pp = p_buf[(atok << 2) + (k0 >> 7)];
            }
        }
        // ---- compute current tile ----
        bf16x8 afr[2], bfr[8];
        #pragma unroll
        for (int m = 0; m < 2; ++m)
            afr[m] = *reinterpret_cast<const bf16x8*>(&Alds[cur][og][(m << 4) + lr][0]);
        #pragma unroll
        for (int n = 0; n < 8; ++n)
            bfr[n] = *reinterpret_cast<const bf16x8*>(&Blds[cur][og][(wc << 7) + (n << 4) + lr][0]);
        #pragma unroll
        for (int m = 0; m < 2; ++m)
            #pragma unroll
            for (int n = 0; n < 8; ++n)
                acc[m][n] = __builtin_amdgcn_mfma_f32_16x16x32_bf16(afr[m], bfr[n], acc[m][n], 0, 0, 0);
        // ---- finish staging next tile, single barrier ----
        if (kt16 < 15) {
            float4 av = bv;
            if (FUSED) {
                av.x = fmaf(pp, h0.x, bv.x); av.y = fmaf(pp, h0.y, bv.y);
                av.z = fmaf(pp, h0.z, bv.z); av.w = fmaf(pp, h0.w, bv.w);
            }
            *reinterpret_cast<unsigned long long*>(&Alds[cur ^ 1][aq >> 1][arow][(aq & 1) << 2]) = pack4bf(av);
            __syncthreads();   // drains vmcnt (B landed) + lgkm, publishes A
        }
    }

    // ---- epilogue: C/D layout col=lane&15, row=(lane>>4)*4+reg ----
    #pragma unroll
    for (int m = 0; m < 2; ++m) {
        const long rb = t0 + (m << 4) + (og << 2);
        #pragma unroll
        for (int n = 0; n < 8; ++n) {
            const int col = (wc << 7) + (n << 4) + lr;
            #pragma unroll
            for (int j = 0; j < 4; ++j)
                out[(rb + j) * 512 + col] = acc[m][n][j];
        }
    }
}

// ---------------------------------------------------------------------------
// k_lnA: per block = 1 chunk (16 tokens). LayerNorm + gates per token (wave
// handles 4 tokens), bn = beta*xn staged in LDS; then per-chunk cumprod p and
// clamped cumsum B0 = q*cumsum(bn/q), written in place over xp. Fuses what
// were k_ln_gates + k2_phaseA (saves a full 268 MB round trip).
// ---------------------------------------------------------------------------
__global__ __launch_bounds__(256) void k_lnA(
    const float* __restrict__ gamma, const float* __restrict__ beta,
    const float* __restrict__ Wg, const float* __restrict__ bg,
    const float* __restrict__ eig_raw,
    float* io, float* __restrict__ p_buf)
{
    __shared__ float bnS[16][512];   // 32 KB
    __shared__ float qS[16][4];
    __shared__ float aS[16][4];

    const int tid = threadIdx.x;
    const int l = tid & 63, w = tid >> 6;
    const long t0 = (long)blockIdx.x * 16;
    const int c0 = l << 2;

    #pragma unroll
    for (int m = 0; m < 4; ++m) {
        const int r = w * 4 + m;
        const long tok = t0 + r;
        const float4 v0 = *(const float4*)&io[tok * 512 + c0];
        const float4 v1 = *(const float4*)&io[tok * 512 + c0 + 256];

        float s1 = v0.x + v0.y + v0.z + v0.w + v1.x + v1.y + v1.z + v1.w;
        float s2 = v0.x*v0.x + v0.y*v0.y + v0.z*v0.z + v0.w*v0.w
                 + v1.x*v1.x + v1.y*v1.y + v1.z*v1.z + v1.w*v1.w;
        #pragma unroll
        for (int o = 32; o; o >>= 1) { s1 += __shfl_xor(s1, o, 64); s2 += __shfl_xor(s2, o, 64); }
        const float mean = s1 * (1.f/512.f);
        const float var  = s2 * (1.f/512.f) - mean*mean;
        const float rstd = 1.0f / sqrtf(var + 1e-5f);

        const float4 g0 = *(const float4*)&gamma[c0];
        const float4 g1 = *(const float4*)&gamma[c0 + 256];
        const float4 b0 = *(const float4*)&beta[c0];
        const float4 b1 = *(const float4*)&beta[c0 + 256];
        float4 xn0, xn1;
        xn0.x = (v0.x - mean)*rstd*g0.x + b0.x;  xn0.y = (v0.y - mean)*rstd*g0.y + b0.y;
        xn0.z = (v0.z - mean)*rstd*g0.z + b0.z;  xn0.w = (v0.w - mean)*rstd*g0.w + b0.w;
        xn1.x = (v1.x - mean)*rstd*g1.x + b1.x;  xn1.y = (v1.y - mean)*rstd*g1.y + b1.y;
        xn1.z = (v1.z - mean)*rstd*g1.z + b1.z;  xn1.w = (v1.w - mean)*rstd*g1.w + b1.w;

        float gt[8];
        #pragma unroll
        for (int g = 0; g < 8; ++g) {
            const float4 w0 = *(const float4*)&Wg[g * 512 + c0];
            const float4 w1 = *(const float4*)&Wg[g * 512 + c0 + 256];
            float p = xn0.x*w0.x + xn0.y*w0.y + xn0.z*w0.z + xn0.w*w0.w
                    + xn1.x*w1.x + xn1.y*w1.y + xn1.z*w1.z + xn1.w*w1.w;
            #pragma unroll
            for (int o = 32; o; o >>= 1) p += __shfl_xor(p, o, 64);
            gt[g] = p + bg[g];
        }

        const int n0 = l >> 5, n1 = 2 + (l >> 5);
        const float bt0 = sigmoidf_(gt[4 + n0]);
        const float bt1 = sigmoidf_(gt[4 + n1]);
        *(float4*)&bnS[r][c0]       = make_float4(bt0*xn0.x, bt0*xn0.y, bt0*xn0.z, bt0*xn0.w);
        *(float4*)&bnS[r][c0 + 256] = make_float4(bt1*xn1.x, bt1*xn1.y, bt1*xn1.z, bt1*xn1.w);
        if (l < 4) aS[r][l] = tanhf(eig_raw[l]) * sigmoidf_(gt[l]);
    }
    __syncthreads();

    if (tid < 4) {
        const int n = tid;
        float p = 1.f;
        #pragma unroll
        for (int t = 0; t < 16; ++t) {
            p *= aS[t][n];
            p_buf[(t0 + t) * 4 + n] = p;
            qS[t][n] = fmaxf(p, 1e-6f);
        }
    }
    __syncthreads();

    #pragma unroll
    for (int cc = 0; cc < 2; ++cc) {
        const int c = tid + (cc << 8);
        const int n = c >> 7;
        float s = 0.f;
        #pragma unroll
        for (int t = 0; t < 16; ++t) {
            const float q = qS[t][n];
            s += bnS[t][c] / q;
            io[(t0 + t) * 512 + c] = q * s;
        }
    }
}

// ---------------------------------------------------------------------------
// k3 (phase B): sequential scan over 512 chunk carries, 4096 parallel lanes.
// ---------------------------------------------------------------------------
__global__ __launch_bounds__(256) void k3_scan(
    const float* __restrict__ p_buf, const float* __restrict__ bvec,
    const float* __restrict__ h_in, float* __restrict__ h0_buf,
    float* __restrict__ h_last)
{
    const int tid = blockIdx.x * blockDim.x + threadIdx.x; // 0..4095
    const int b = tid >> 9, c = tid & 511, n = c >> 7;
    float h = h_in[b * DH_ + c];
    for (int ch = 0; ch < NC_; ++ch) {
        h0_buf[((long)(b * NC_ + ch)) * DH_ + c] = h;
        long sE = (long)b * S_ + (long)ch * CHUNK_ + (CHUNK_ - 1);
        float p15 = p_buf[sE * HN_ + n];
        float B15 = bvec[sE * DH_ + c];
        h = fmaf(p15, h, B15);
    }
    h_last[b * DH_ + c] = h;
}

extern "C" void kernel_launch(void* const* d_in, const int* in_sizes, int n_in,
                              void* d_out, int out_size, void* d_ws, size_t ws_size,
                              hipStream_t stream) {
    const float* x       = (const float*)d_in[0];
    const float* h       = (const float*)d_in[1];
    const float* Win     = (const float*)d_in[2];
    const float* gamma   = (const float*)d_in[3];
    const float* beta    = (const float*)d_in[4];
    const float* Wg      = (const float*)d_in[5];
    const float* bg      = (const float*)d_in[6];
    const float* eig_raw = (const float*)d_in[7];
    const float* Wout    = (const float*)d_in[8];

    float* out    = (float*)d_out;                 // xp -> B0 -> (h_all fused) -> out
    float* h_last = out + (long)NTOK * DH_;

    float* ws     = (float*)d_ws;
    float* p_buf  = ws;                            // 262144 f
    float* h0_buf = ws + 262144;                   // 2097152 f
    unsigned short* WreA = (unsigned short*)(ws + 2359296);  // 262144 us
    unsigned short* WreB = WreA + 262144;                    // 262144 us

    k0_convert<<<1024, 256, 0, stream>>>(Win, Wout, WreA, WreB);
    gemm_rows<false><<<NTOK/32, 256, 0, stream>>>(x, WreA, nullptr, nullptr, out);
    k_lnA<<<NTOK/16, 256, 0, stream>>>(gamma, beta, Wg, bg, eig_raw, out, p_buf);
    k3_scan<<<16, 256, 0, stream>>>(p_buf, out, h, h0_buf, h_last);
    gemm_rows<true><<<NTOK/32, 256, 0, stream>>>(out, WreB, p_buf, h0_buf, out);
}

// Round 5
// 266.382 us; speedup vs baseline: 1.2416x; 1.2291x over previous
//
#include <hip/hip_runtime.h>
#include <hip/hip_bf16.h>
#include <math.h>

#define B_    8
#define S_    8192
#define DIN_  512
#define DH_   512
#define HN_   4
#define HD_   128
#define CHUNK_ 16
#define NC_   (S_/CHUNK_)
#define NTOK  (B_*S_)

typedef __bf16 bf16x8 __attribute__((ext_vector_type(8)));
typedef float  f32x4  __attribute__((ext_vector_type(4)));

__device__ __forceinline__ float sigmoidf_(float z) { return 1.0f / (1.0f + expf(-z)); }

__device__ __forceinline__ unsigned short f2bf(float f) {
    union { float f; unsigned u; } v; v.f = f;
    unsigned u = v.u;
    u += 0x7fffu + ((u >> 16) & 1u);   // RNE
    return (unsigned short)(u >> 16);
}
__device__ __forceinline__ unsigned long long pack4bf(float4 a) {
    return (unsigned long long)f2bf(a.x)
         | ((unsigned long long)f2bf(a.y) << 16)
         | ((unsigned long long)f2bf(a.z) << 32)
         | ((unsigned long long)f2bf(a.w) << 48);
}
__device__ __forceinline__ void gload_lds16(const void* g, void* lds) {
    __builtin_amdgcn_global_load_lds(
        (const __attribute__((address_space(1))) unsigned int*)g,
        (__attribute__((address_space(3))) unsigned int*)lds, 16, 0, 0);
}

// ---------------------------------------------------------------------------
// k0: convert W_in / W_out f32 -> bf16, pre-permuted to LDS layout:
//   Wre[kt16][og][c][kk] = W[c][kt16*32 + og*8 + kk]
// ---------------------------------------------------------------------------
__global__ __launch_bounds__(256) void k0_convert(
    const float* __restrict__ Win, const float* __restrict__ Wout,
    unsigned short* __restrict__ WreA, unsigned short* __restrict__ WreB)
{
    int idx = blockIdx.x * 256 + threadIdx.x;
    if (idx < 262144) {
        int c = idx >> 9, k = idx & 511;
        int dst = ((k >> 5) << 14) + (((k >> 3) & 3) << 12) + (c << 3) + (k & 7);
        WreA[dst] = f2bf(Win[idx]);
        WreB[dst] = f2bf(Wout[idx]);
    }
}

// ---------------------------------------------------------------------------
// gemm1: xp = x @ Win^T. BM=64, 4 waves, acc[4][8] (32 MFMA / K-step / wave),
// single-buffered LDS (36 KB). A packed f32->bf16 in-kernel.
// ---------------------------------------------------------------------------
__global__ __launch_bounds__(256, 2) void gemm1(
    const float* __restrict__ x, const unsigned short* __restrict__ Wre,
    float* __restrict__ out)
{
    __shared__ alignas(16) unsigned short Blds[4][512][8];  // 32 KB
    __shared__ alignas(16) unsigned short Alds[4][64][8];   // 4 KB
    const int tid = threadIdx.x;
    const int l = tid & 63, wc = tid >> 6;
    const int og = l >> 4, lr = l & 15;
    const long t0 = (long)blockIdx.x * 64;

    f32x4 acc[4][8];
    #pragma unroll
    for (int m = 0; m < 4; ++m)
        #pragma unroll
        for (int n = 0; n < 8; ++n) acc[m][n] = (f32x4)(0.f);

    for (int kt16 = 0; kt16 < 16; ++kt16) {
        __syncthreads();
        const char* gW = (const char*)Wre + ((long)kt16 << 15);
        char* lB = (char*)&Blds[0][0][0] + (wc << 10);
        #pragma unroll
        for (int i = 0; i < 8; ++i)
            gload_lds16(gW + (i << 12) + (wc << 10) + (l << 4), lB + (i << 12));
        #pragma unroll
        for (int s = 0; s < 2; ++s) {
            int f4i = tid + (s << 8);
            int row = f4i >> 3, q = f4i & 7;
            float4 av = *(const float4*)&x[(t0 + row) * 512 + (kt16 << 5) + (q << 2)];
            *reinterpret_cast<unsigned long long*>(&Alds[q >> 1][row][(q & 1) << 2]) = pack4bf(av);
        }
        __syncthreads();

        bf16x8 afr[4], bfr[8];
        #pragma unroll
        for (int m = 0; m < 4; ++m)
            afr[m] = *reinterpret_cast<const bf16x8*>(&Alds[og][(m << 4) + lr][0]);
        #pragma unroll
        for (int n = 0; n < 8; ++n)
            bfr[n] = *reinterpret_cast<const bf16x8*>(&Blds[og][(wc << 7) + (n << 4) + lr][0]);
        #pragma unroll
        for (int m = 0; m < 4; ++m)
            #pragma unroll
            for (int n = 0; n < 8; ++n)
                acc[m][n] = __builtin_amdgcn_mfma_f32_16x16x32_bf16(afr[m], bfr[n], acc[m][n], 0, 0, 0);
    }

    #pragma unroll
    for (int m = 0; m < 4; ++m) {
        const long rb = t0 + (m << 4) + (og << 2);
        #pragma unroll
        for (int n = 0; n < 8; ++n) {
            const int col = (wc << 7) + (n << 4) + lr;
            #pragma unroll
            for (int j = 0; j < 4; ++j)
                out[(rb + j) * 512 + col] = acc[m][n][j];
        }
    }
}

// ---------------------------------------------------------------------------
// k_lnA: block = 1 chunk (16 tokens). LN + gates (Wg staged in LDS) ->
// bn=beta*xn in LDS -> cumprod p (p_buf) -> clamped cumsum B0 in LDS ->
// B15 f32 (for scan) + B0 packed bf16 into gemm2's A-LDS layout (A2).
// ---------------------------------------------------------------------------
__global__ __launch_bounds__(256) void k_lnA(
    const float* __restrict__ xp,
    const float* __restrict__ gamma, const float* __restrict__ beta,
    const float* __restrict__ Wg, const float* __restrict__ bg,
    const float* __restrict__ eig_raw,
    unsigned short* __restrict__ A2, float* __restrict__ B15,
    float* __restrict__ p_buf)
{
    __shared__ float bnS[16][512];   // 32 KB
    __shared__ float WgL[8][512];    // 16 KB
    __shared__ float qS[16][4];
    __shared__ float aS[16][4];

    const int tid = threadIdx.x;
    const int l = tid & 63, w = tid >> 6;
    const long t0 = (long)blockIdx.x * 16;
    const int c0 = l << 2;

    #pragma unroll
    for (int i = 0; i < 4; ++i)
        ((float4*)WgL)[tid + 256 * i] = ((const float4*)Wg)[tid + 256 * i];
    __syncthreads();

    #pragma unroll
    for (int m = 0; m < 4; ++m) {
        const int r = w * 4 + m;
        const long tok = t0 + r;
        const float4 v0 = *(const float4*)&xp[tok * 512 + c0];
        const float4 v1 = *(const float4*)&xp[tok * 512 + c0 + 256];

        float s1 = v0.x + v0.y + v0.z + v0.w + v1.x + v1.y + v1.z + v1.w;
        float s2 = v0.x*v0.x + v0.y*v0.y + v0.z*v0.z + v0.w*v0.w
                 + v1.x*v1.x + v1.y*v1.y + v1.z*v1.z + v1.w*v1.w;
        #pragma unroll
        for (int o = 32; o; o >>= 1) { s1 += __shfl_xor(s1, o, 64); s2 += __shfl_xor(s2, o, 64); }
        const float mean = s1 * (1.f/512.f);
        const float var  = s2 * (1.f/512.f) - mean*mean;
        const float rstd = 1.0f / sqrtf(var + 1e-5f);

        const float4 g0 = *(const float4*)&gamma[c0];
        const float4 g1 = *(const float4*)&gamma[c0 + 256];
        const float4 b0 = *(const float4*)&beta[c0];
        const float4 b1 = *(const float4*)&beta[c0 + 256];
        float4 xn0, xn1;
        xn0.x = (v0.x - mean)*rstd*g0.x + b0.x;  xn0.y = (v0.y - mean)*rstd*g0.y + b0.y;
        xn0.z = (v0.z - mean)*rstd*g0.z + b0.z;  xn0.w = (v0.w - mean)*rstd*g0.w + b0.w;
        xn1.x = (v1.x - mean)*rstd*g1.x + b1.x;  xn1.y = (v1.y - mean)*rstd*g1.y + b1.y;
        xn1.z = (v1.z - mean)*rstd*g1.z + b1.z;  xn1.w = (v1.w - mean)*rstd*g1.w + b1.w;

        float gt[8];
        #pragma unroll
        for (int g = 0; g < 8; ++g) {
            const float4 w0 = *(const float4*)&WgL[g][c0];
            const float4 w1 = *(const float4*)&WgL[g][c0 + 256];
            float p = xn0.x*w0.x + xn0.y*w0.y + xn0.z*w0.z + xn0.w*w0.w
                    + xn1.x*w1.x + xn1.y*w1.y + xn1.z*w1.z + xn1.w*w1.w;
            #pragma unroll
            for (int o = 32; o; o >>= 1) p += __shfl_xor(p, o, 64);
            gt[g] = p + bg[g];
        }

        const int n0 = l >> 5, n1 = 2 + (l >> 5);
        const float bt0 = sigmoidf_(gt[4 + n0]);
        const float bt1 = sigmoidf_(gt[4 + n1]);
        *(float4*)&bnS[r][c0]       = make_float4(bt0*xn0.x, bt0*xn0.y, bt0*xn0.z, bt0*xn0.w);
        *(float4*)&bnS[r][c0 + 256] = make_float4(bt1*xn1.x, bt1*xn1.y, bt1*xn1.z, bt1*xn1.w);
        if (l < 4) aS[r][l] = tanhf(eig_raw[l]) * sigmoidf_(gt[l]);
    }
    __syncthreads();

    if (tid < 4) {
        const int n = tid;
        float p = 1.f;
        #pragma unroll
        for (int t = 0; t < 16; ++t) {
            p *= aS[t][n];
            p_buf[(t0 + t) * 4 + n] = p;
            qS[t][n] = fmaxf(p, 1e-6f);
        }
    }
    __syncthreads();

    // clamped cumsum, in place in LDS; B15 (t=15) to global f32
    #pragma unroll
    for (int cc = 0; cc < 2; ++cc) {
        const int c = tid + (cc << 8);
        const int n = c >> 7;
        float s = 0.f;
        #pragma unroll
        for (int t = 0; t < 16; ++t) {
            const float q = qS[t][n];
            s += bnS[t][c] / q;
            const float v = q * s;
            bnS[t][c] = v;
            if (t == 15) B15[blockIdx.x * 512 + c] = v;
        }
    }
    __syncthreads();

    // pack B0 -> A2 bf16 in gemm2's A-tile layout:
    // A2[((T>>6)*16 + kt16)*2048 + og*512 + (T&63)*8 + kk]
    #pragma unroll
    for (int i = 0; i < 8; ++i) {
        const int slot = (i << 8) + tid;          // 2048 slots = 16 t x 128 quads
        const int t = slot >> 7, qd = slot & 127;
        const float4 v = *(const float4*)&bnS[t][qd << 2];
        const long T = t0 + t;
        const long addr = ((T >> 6) * 16 + (qd >> 3)) * 2048
                        + ((qd >> 1) & 3) * 512 + (T & 63) * 8 + (qd & 1) * 4;
        *reinterpret_cast<unsigned long long*>(&A2[addr]) = pack4bf(v);
    }
}

// ---------------------------------------------------------------------------
// k3: sequential scan over 512 chunk carries, 4096 parallel lanes (f32).
// ---------------------------------------------------------------------------
__global__ __launch_bounds__(256) void k3_scan(
    const float* __restrict__ p_buf, const float* __restrict__ B15,
    const float* __restrict__ h_in, float* __restrict__ h0_buf,
    float* __restrict__ h_last)
{
    const int tid = blockIdx.x * blockDim.x + threadIdx.x; // 0..4095
    const int b = tid >> 9, c = tid & 511, n = c >> 7;
    float h = h_in[b * DH_ + c];
    for (int ch = 0; ch < NC_; ++ch) {
        const long gc = b * NC_ + ch;
        h0_buf[gc * 512 + c] = h;
        const long sE = (long)b * S_ + (long)ch * CHUNK_ + (CHUNK_ - 1);
        h = fmaf(p_buf[sE * HN_ + n], h, B15[gc * 512 + c]);
    }
    h_last[b * DH_ + c] = h;
}

// ---------------------------------------------------------------------------
// kG: G[hn][gc][col] = sum_{d in hn-slice} h0[gc][d] * Wout[col][d].
// 4 thin GEMMs (M=4096 chunks, N=512, K=128) via MFMA; BM=64.
// ---------------------------------------------------------------------------
__global__ __launch_bounds__(256, 2) void kG(
    const float* __restrict__ h0, const unsigned short* __restrict__ WreB,
    float* __restrict__ G)
{
    __shared__ alignas(16) unsigned short Blds[4][512][8];
    __shared__ alignas(16) unsigned short Alds[4][64][8];
    const int tid = threadIdx.x;
    const int l = tid & 63, wc = tid >> 6;
    const int og = l >> 4, lr = l & 15;
    const int hn = blockIdx.x >> 6;
    const long c0 = (long)(blockIdx.x & 63) * 64;

    f32x4 acc[4][8];
    #pragma unroll
    for (int m = 0; m < 4; ++m)
        #pragma unroll
        for (int n = 0; n < 8; ++n) acc[m][n] = (f32x4)(0.f);

    for (int s = 0; s < 4; ++s) {
        const int kt16 = (hn << 2) + s;
        __syncthreads();
        const char* gW = (const char*)WreB + ((long)kt16 << 15);
        char* lB = (char*)&Blds[0][0][0] + (wc << 10);
        #pragma unroll
        for (int i = 0; i < 8; ++i)
            gload_lds16(gW + (i << 12) + (wc << 10) + (l << 4), lB + (i << 12));
        #pragma unroll
        for (int ss = 0; ss < 2; ++ss) {
            int f4i = tid + (ss << 8);
            int row = f4i >> 3, q = f4i & 7;
            float4 av = *(const float4*)&h0[(c0 + row) * 512 + (hn << 7) + (s << 5) + (q << 2)];
            *reinterpret_cast<unsigned long long*>(&Alds[q >> 1][row][(q & 1) << 2]) = pack4bf(av);
        }
        __syncthreads();

        bf16x8 afr[4], bfr[8];
        #pragma unroll
        for (int m = 0; m < 4; ++m)
            afr[m] = *reinterpret_cast<const bf16x8*>(&Alds[og][(m << 4) + lr][0]);
        #pragma unroll
        for (int n = 0; n < 8; ++n)
            bfr[n] = *reinterpret_cast<const bf16x8*>(&Blds[og][(wc << 7) + (n << 4) + lr][0]);
        #pragma unroll
        for (int m = 0; m < 4; ++m)
            #pragma unroll
            for (int n = 0; n < 8; ++n)
                acc[m][n] = __builtin_amdgcn_mfma_f32_16x16x32_bf16(afr[m], bfr[n], acc[m][n], 0, 0, 0);
    }

    float* Gh = G + (long)hn * (4096L * 512);
    #pragma unroll
    for (int m = 0; m < 4; ++m) {
        const long rb = c0 + (m << 4) + (og << 2);
        #pragma unroll
        for (int n = 0; n < 8; ++n) {
            const int col = (wc << 7) + (n << 4) + lr;
            #pragma unroll
            for (int j = 0; j < 4; ++j)
                Gh[(rb + j) * 512 + col] = acc[m][n][j];
        }
    }
}

// ---------------------------------------------------------------------------
// gemm2: out = B0 @ Wout^T + p.G  (phase C folded into epilogue).
// A = A2 (bf16 pre-packed): pure global_load_lds staging, no pack VALU.
// ---------------------------------------------------------------------------
__global__ __launch_bounds__(256, 2) void gemm2(
    const unsigned short* __restrict__ A2, const unsigned short* __restrict__ Wre,
    const float* __restrict__ G, const float* __restrict__ p_buf,
    float* __restrict__ out)
{
    __shared__ alignas(16) unsigned short Blds[4][512][8];  // 32 KB
    __shared__ alignas(16) unsigned short Alds[4][64][8];   // 4 KB
    __shared__ float pS[64][4];                             // 1 KB
    const int tid = threadIdx.x;
    const int l = tid & 63, wc = tid >> 6;
    const int og = l >> 4, lr = l & 15;
    const long t0 = (long)blockIdx.x * 64;

    f32x4 acc[4][8];
    #pragma unroll
    for (int m = 0; m < 4; ++m)
        #pragma unroll
        for (int n = 0; n < 8; ++n) acc[m][n] = (f32x4)(0.f);

    for (int kt16 = 0; kt16 < 16; ++kt16) {
        __syncthreads();
        const char* gW = (const char*)Wre + ((long)kt16 << 15);
        char* lB = (char*)&Blds[0][0][0] + (wc << 10);
        #pragma unroll
        for (int i = 0; i < 8; ++i)
            gload_lds16(gW + (i << 12) + (wc << 10) + (l << 4), lB + (i << 12));
        // A tile: 4 KB contiguous DMA
        const char* gA = (const char*)A2 + (((t0 >> 6) * 16 + kt16) << 12);
        gload_lds16(gA + (tid << 4), (char*)&Alds[0][0][0] + (tid << 4));
        __syncthreads();

        bf16x8 afr[4], bfr[8];
        #pragma unroll
        for (int m = 0; m < 4; ++m)
            afr[m] = *reinterpret_cast<const bf16x8*>(&Alds[og][(m << 4) + lr][0]);
        #pragma unroll
        for (int n = 0; n < 8; ++n)
            bfr[n] = *reinterpret_cast<const bf16x8*>(&Blds[og][(wc << 7) + (n << 4) + lr][0]);
        #pragma unroll
        for (int m = 0; m < 4; ++m)
            #pragma unroll
            for (int n = 0; n < 8; ++n)
                acc[m][n] = __builtin_amdgcn_mfma_f32_16x16x32_bf16(afr[m], bfr[n], acc[m][n], 0, 0, 0);
    }

    // stage p for the block's 64 tokens
    pS[tid >> 2][tid & 3] = p_buf[t0 * 4 + tid];
    __syncthreads();

    #pragma unroll
    for (int m = 0; m < 4; ++m) {
        const long gc = (t0 >> 4) + m;
        #pragma unroll
        for (int n = 0; n < 8; ++n) {
            const int col = (wc << 7) + (n << 4) + lr;
            const float g0 = G[gc * 512 + col];
            const float g1 = G[2097152L + gc * 512 + col];
            const float g2 = G[4194304L + gc * 512 + col];
            const float g3 = G[6291456L + gc * 512 + col];
            #pragma unroll
            for (int j = 0; j < 4; ++j) {
                const int rl = (m << 4) + (og << 2) + j;
                const float add = pS[rl][0]*g0 + pS[rl][1]*g1 + pS[rl][2]*g2 + pS[rl][3]*g3;
                out[(t0 + rl) * 512 + col] = acc[m][n][j] + add;
            }
        }
    }
}

extern "C" void kernel_launch(void* const* d_in, const int* in_sizes, int n_in,
                              void* d_out, int out_size, void* d_ws, size_t ws_size,
                              hipStream_t stream) {
    const float* x       = (const float*)d_in[0];
    const float* h       = (const float*)d_in[1];
    const float* Win     = (const float*)d_in[2];
    const float* gamma   = (const float*)d_in[3];
    const float* beta    = (const float*)d_in[4];
    const float* Wg      = (const float*)d_in[5];
    const float* bg      = (const float*)d_in[6];
    const float* eig_raw = (const float*)d_in[7];
    const float* Wout    = (const float*)d_in[8];

    float* out    = (float*)d_out;                 // xp, then final out
    float* h_last = out + (long)NTOK * DH_;

    float* ws     = (float*)d_ws;
    float* p_buf  = ws;                            //  262144 f
    float* h0_buf = ws + 262144;                   // 2097152 f
    float* B15    = ws + 2359296;                  // 2097152 f
    float* G      = ws + 4456448;                  // 8388608 f
    unsigned short* WreA = (unsigned short*)(ws + 12845056);  // 262144 us
    unsigned short* WreB = WreA + 262144;                     // 262144 us
    unsigned short* A2   = (unsigned short*)(ws + 13107200);  // 33554432 us

    k0_convert<<<1024, 256, 0, stream>>>(Win, Wout, WreA, WreB);
    gemm1<<<NTOK/64, 256, 0, stream>>>(x, WreA, out);
    k_lnA<<<NTOK/16, 256, 0, stream>>>(out, gamma, beta, Wg, bg, eig_raw,
                                       A2, B15, p_buf);
    k3_scan<<<16, 256, 0, stream>>>(p_buf, B15, h, h0_buf, h_last);
    kG<<<256, 256, 0, stream>>>(h0_buf, WreB, G);
    gemm2<<<NTOK/64, 256, 0, stream>>>(A2, WreB, G, p_buf, out);
}

// Round 6
// 257.952 us; speedup vs baseline: 1.2822x; 1.0327x over previous
//
#include <hip/hip_runtime.h>
#include <hip/hip_bf16.h>
#include <math.h>

#define B_    8
#define S_    8192
#define DIN_  512
#define DH_   512
#define HN_   4
#define HD_   128
#define CHUNK_ 16
#define NC_   (S_/CHUNK_)
#define NTOK  (B_*S_)

typedef __bf16 bf16x8 __attribute__((ext_vector_type(8)));
typedef float  f32x4  __attribute__((ext_vector_type(4)));

__device__ __forceinline__ float sigmoidf_(float z) { return 1.0f / (1.0f + expf(-z)); }

__device__ __forceinline__ unsigned short f2bf(float f) {
    union { float f; unsigned u; } v; v.f = f;
    unsigned u = v.u;
    u += 0x7fffu + ((u >> 16) & 1u);   // RNE
    return (unsigned short)(u >> 16);
}
__device__ __forceinline__ unsigned long long pack4bf(float4 a) {
    return (unsigned long long)f2bf(a.x)
         | ((unsigned long long)f2bf(a.y) << 16)
         | ((unsigned long long)f2bf(a.z) << 32)
         | ((unsigned long long)f2bf(a.w) << 48);
}
__device__ __forceinline__ void gload_lds16(const void* g, void* lds) {
    __builtin_amdgcn_global_load_lds(
        (const __attribute__((address_space(1))) unsigned int*)g,
        (__attribute__((address_space(3))) unsigned int*)lds, 16, 0, 0);
}

// ---------------------------------------------------------------------------
// k0: convert W_in / W_out f32 -> bf16, pre-permuted to LDS layout:
//   Wre[kt16][og][c][kk] = W[c][kt16*32 + og*8 + kk]
// ---------------------------------------------------------------------------
__global__ __launch_bounds__(256) void k0_convert(
    const float* __restrict__ Win, const float* __restrict__ Wout,
    unsigned short* __restrict__ WreA, unsigned short* __restrict__ WreB)
{
    int idx = blockIdx.x * 256 + threadIdx.x;
    if (idx < 262144) {
        int c = idx >> 9, k = idx & 511;
        int dst = ((k >> 5) << 14) + (((k >> 3) & 3) << 12) + (c << 3) + (k & 7);
        WreA[dst] = f2bf(Win[idx]);
        WreB[dst] = f2bf(Wout[idx]);
    }
}

// ---------------------------------------------------------------------------
// gemm1: xp = x @ Win^T. BM=64, acc[4][8], DOUBLE-BUFFERED (T3 2-phase):
// next tile's B gload_lds + A reg-loads issued BEFORE current tile's MFMA;
// one barrier per K-step.
// ---------------------------------------------------------------------------
__global__ __launch_bounds__(256, 2) void gemm1(
    const float* __restrict__ x, const unsigned short* __restrict__ Wre,
    float* __restrict__ out)
{
    __shared__ alignas(16) unsigned short Blds[2][4][512][8];  // 64 KB
    __shared__ alignas(16) unsigned short Alds[2][4][64][8];   // 8 KB
    const int tid = threadIdx.x;
    const int l = tid & 63, wc = tid >> 6;
    const int og = l >> 4, lr = l & 15;
    const long t0 = (long)blockIdx.x * 64;
    const int row0 = tid >> 3, q0 = tid & 7;          // A slot 0
    const int row1 = (tid + 256) >> 3, q1 = tid & 7;  // A slot 1

    f32x4 acc[4][8];
    #pragma unroll
    for (int m = 0; m < 4; ++m)
        #pragma unroll
        for (int n = 0; n < 8; ++n) acc[m][n] = (f32x4)(0.f);

    // ---- prologue: stage tile 0 into buf 0 ----
    {
        const char* gW = (const char*)Wre;
        char* lB = (char*)&Blds[0][0][0][0] + (wc << 10);
        #pragma unroll
        for (int i = 0; i < 8; ++i)
            gload_lds16(gW + (i << 12) + (wc << 10) + (l << 4), lB + (i << 12));
        float4 a0 = *(const float4*)&x[(t0 + row0) * 512 + (q0 << 2)];
        float4 a1 = *(const float4*)&x[(t0 + row1) * 512 + (q1 << 2)];
        *reinterpret_cast<unsigned long long*>(&Alds[0][q0 >> 1][row0][(q0 & 1) << 2]) = pack4bf(a0);
        *reinterpret_cast<unsigned long long*>(&Alds[0][q1 >> 1][row1][(q1 & 1) << 2]) = pack4bf(a1);
    }
    __syncthreads();

    for (int kt16 = 0; kt16 < 16; ++kt16) {
        const int cur = kt16 & 1;
        float4 a0, a1;
        if (kt16 < 15) {
            const char* gW = (const char*)Wre + ((long)(kt16 + 1) << 15);
            char* lB = (char*)&Blds[cur ^ 1][0][0][0] + (wc << 10);
            #pragma unroll
            for (int i = 0; i < 8; ++i)
                gload_lds16(gW + (i << 12) + (wc << 10) + (l << 4), lB + (i << 12));
            const int k0 = ((kt16 + 1) << 5);
            a0 = *(const float4*)&x[(t0 + row0) * 512 + k0 + (q0 << 2)];
            a1 = *(const float4*)&x[(t0 + row1) * 512 + k0 + (q1 << 2)];
        }
        // ---- compute current tile ----
        bf16x8 afr[4], bfr[8];
        #pragma unroll
        for (int m = 0; m < 4; ++m)
            afr[m] = *reinterpret_cast<const bf16x8*>(&Alds[cur][og][(m << 4) + lr][0]);
        #pragma unroll
        for (int n = 0; n < 8; ++n)
            bfr[n] = *reinterpret_cast<const bf16x8*>(&Blds[cur][og][(wc << 7) + (n << 4) + lr][0]);
        #pragma unroll
        for (int m = 0; m < 4; ++m)
            #pragma unroll
            for (int n = 0; n < 8; ++n)
                acc[m][n] = __builtin_amdgcn_mfma_f32_16x16x32_bf16(afr[m], bfr[n], acc[m][n], 0, 0, 0);
        if (kt16 < 15) {
            *reinterpret_cast<unsigned long long*>(&Alds[cur ^ 1][q0 >> 1][row0][(q0 & 1) << 2]) = pack4bf(a0);
            *reinterpret_cast<unsigned long long*>(&Alds[cur ^ 1][q1 >> 1][row1][(q1 & 1) << 2]) = pack4bf(a1);
            __syncthreads();   // drains vmcnt (B landed) + lgkm (A visible)
        }
    }

    #pragma unroll
    for (int m = 0; m < 4; ++m) {
        const long rb = t0 + (m << 4) + (og << 2);
        #pragma unroll
        for (int n = 0; n < 8; ++n) {
            const int col = (wc << 7) + (n << 4) + lr;
            #pragma unroll
            for (int j = 0; j < 4; ++j)
                out[(rb + j) * 512 + col] = acc[m][n][j];
        }
    }
}

// ---------------------------------------------------------------------------
// k_lnA: block = 1 chunk (16 tokens). TOKEN-PARALLEL: 16 lanes per token
// (4 tokens per wave concurrently), 32 cols per lane. LN + gate reductions
// are 4-step 16-lane butterflies shared across the wave's 4 tokens.
// Then cumprod p (p_buf), clamped cumsum B0 (rq-multiply), B15 f32,
// B0 packed bf16 into gemm2's A-LDS layout (A2).
// ---------------------------------------------------------------------------
__global__ __launch_bounds__(256) void k_lnA(
    const float* __restrict__ xp,
    const float* __restrict__ gamma, const float* __restrict__ beta,
    const float* __restrict__ Wg, const float* __restrict__ bg,
    const float* __restrict__ eig_raw,
    unsigned short* __restrict__ A2, float* __restrict__ B15,
    float* __restrict__ p_buf)
{
    __shared__ float bnS[16][512];   // 32 KB
    __shared__ float WgL[8][512];    // 16 KB
    __shared__ float qS[16][4];
    __shared__ float rqS[16][4];
    __shared__ float aS[16][4];

    const int tid = threadIdx.x;
    const int l = tid & 63, w = tid >> 6;
    const int lg = l >> 4;           // token within wave
    const int li = l & 15;           // lane within token group
    const int r  = (w << 2) + lg;    // token row in chunk 0..15
    const long t0 = (long)blockIdx.x * 16;
    const long tok = t0 + r;

    // issue xp loads first (long latency), 8 x float4 = 32 cols per lane
    float4 v[8];
    #pragma unroll
    for (int jj = 0; jj < 8; ++jj)
        v[jj] = *(const float4*)&xp[tok * 512 + (jj << 6) + (li << 2)];

    // stage Wg while xp is in flight
    #pragma unroll
    for (int i = 0; i < 4; ++i)
        ((float4*)WgL)[tid + 256 * i] = ((const float4*)Wg)[tid + 256 * i];
    __syncthreads();

    // ---- LayerNorm: 16-lane butterfly ----
    float s1 = 0.f, s2 = 0.f;
    #pragma unroll
    for (int jj = 0; jj < 8; ++jj) {
        s1 += v[jj].x + v[jj].y + v[jj].z + v[jj].w;
        s2 += v[jj].x*v[jj].x + v[jj].y*v[jj].y + v[jj].z*v[jj].z + v[jj].w*v[jj].w;
    }
    #pragma unroll
    for (int o = 1; o < 16; o <<= 1) { s1 += __shfl_xor(s1, o, 64); s2 += __shfl_xor(s2, o, 64); }
    const float mean = s1 * (1.f/512.f);
    const float var  = s2 * (1.f/512.f) - mean*mean;
    const float rstd = 1.0f / sqrtf(var + 1e-5f);

    #pragma unroll
    for (int jj = 0; jj < 8; ++jj) {
        const float4 g = *(const float4*)&gamma[(jj << 6) + (li << 2)];
        const float4 b = *(const float4*)&beta[(jj << 6) + (li << 2)];
        v[jj].x = (v[jj].x - mean)*rstd*g.x + b.x;
        v[jj].y = (v[jj].y - mean)*rstd*g.y + b.y;
        v[jj].z = (v[jj].z - mean)*rstd*g.z + b.z;
        v[jj].w = (v[jj].w - mean)*rstd*g.w + b.w;
    }

    // ---- gates: 8 dots, 16-lane butterflies ----
    float gt[8];
    #pragma unroll
    for (int g = 0; g < 8; ++g) {
        float p = 0.f;
        #pragma unroll
        for (int jj = 0; jj < 8; ++jj) {
            const float4 wv = *(const float4*)&WgL[g][(jj << 6) + (li << 2)];
            p = fmaf(v[jj].x, wv.x, p); p = fmaf(v[jj].y, wv.y, p);
            p = fmaf(v[jj].z, wv.z, p); p = fmaf(v[jj].w, wv.w, p);
        }
        #pragma unroll
        for (int o = 1; o < 16; o <<= 1) p += __shfl_xor(p, o, 64);
        gt[g] = p + bg[g];
    }

    const float bt0 = sigmoidf_(gt[4]), bt1 = sigmoidf_(gt[5]);
    const float bt2 = sigmoidf_(gt[6]), bt3 = sigmoidf_(gt[7]);
    const float bt[4] = {bt0, bt1, bt2, bt3};
    #pragma unroll
    for (int jj = 0; jj < 8; ++jj) {
        const float b = bt[jj >> 1];
        *(float4*)&bnS[r][(jj << 6) + (li << 2)] =
            make_float4(b*v[jj].x, b*v[jj].y, b*v[jj].z, b*v[jj].w);
    }
    if (li < 4) aS[r][li] = tanhf(eig_raw[li]) * sigmoidf_(gt[li]);
    __syncthreads();

    // ---- per-chunk cumprod ----
    if (tid < 4) {
        const int n = tid;
        float p = 1.f;
        #pragma unroll
        for (int t = 0; t < 16; ++t) {
            p *= aS[t][n];
            p_buf[(t0 + t) * 4 + n] = p;
            const float q = fmaxf(p, 1e-6f);
            qS[t][n] = q;
            rqS[t][n] = 1.0f / q;
        }
    }
    __syncthreads();

    // ---- clamped cumsum in LDS; B15 (t=15) to global f32 ----
    #pragma unroll
    for (int cc = 0; cc < 2; ++cc) {
        const int c = tid + (cc << 8);
        const int n = c >> 7;
        float s = 0.f;
        #pragma unroll
        for (int t = 0; t < 16; ++t) {
            s = fmaf(bnS[t][c], rqS[t][n], s);
            const float vv = qS[t][n] * s;
            bnS[t][c] = vv;
            if (t == 15) B15[blockIdx.x * 512 + c] = vv;
        }
    }
    __syncthreads();

    // ---- pack B0 -> A2 bf16 in gemm2's A-tile layout ----
    #pragma unroll
    for (int i = 0; i < 8; ++i) {
        const int slot = (i << 8) + tid;          // 2048 slots = 16 t x 128 quads
        const int t = slot >> 7, qd = slot & 127;
        const float4 vv = *(const float4*)&bnS[t][qd << 2];
        const long T = t0 + t;
        const long addr = ((T >> 6) * 16 + (qd >> 3)) * 2048
                        + ((qd >> 1) & 3) * 512 + (T & 63) * 8 + (qd & 1) * 4;
        *reinterpret_cast<unsigned long long*>(&A2[addr]) = pack4bf(vv);
    }
}

// ---------------------------------------------------------------------------
// k3: sequential scan over 512 chunk carries, 4096 parallel lanes (f32).
// ---------------------------------------------------------------------------
__global__ __launch_bounds__(256) void k3_scan(
    const float* __restrict__ p_buf, const float* __restrict__ B15,
    const float* __restrict__ h_in, float* __restrict__ h0_buf,
    float* __restrict__ h_last)
{
    const int tid = blockIdx.x * blockDim.x + threadIdx.x; // 0..4095
    const int b = tid >> 9, c = tid & 511, n = c >> 7;
    float h = h_in[b * DH_ + c];
    for (int ch = 0; ch < NC_; ++ch) {
        const long gc = b * NC_ + ch;
        h0_buf[gc * 512 + c] = h;
        const long sE = (long)b * S_ + (long)ch * CHUNK_ + (CHUNK_ - 1);
        h = fmaf(p_buf[sE * HN_ + n], h, B15[gc * 512 + c]);
    }
    h_last[b * DH_ + c] = h;
}

// ---------------------------------------------------------------------------
// kG: G[hn][gc][col] = sum_{d in hn-slice} h0[gc][d] * Wout[col][d].
// ---------------------------------------------------------------------------
__global__ __launch_bounds__(256, 2) void kG(
    const float* __restrict__ h0, const unsigned short* __restrict__ WreB,
    float* __restrict__ G)
{
    __shared__ alignas(16) unsigned short Blds[4][512][8];
    __shared__ alignas(16) unsigned short Alds[4][64][8];
    const int tid = threadIdx.x;
    const int l = tid & 63, wc = tid >> 6;
    const int og = l >> 4, lr = l & 15;
    const int hn = blockIdx.x >> 6;
    const long c0 = (long)(blockIdx.x & 63) * 64;

    f32x4 acc[4][8];
    #pragma unroll
    for (int m = 0; m < 4; ++m)
        #pragma unroll
        for (int n = 0; n < 8; ++n) acc[m][n] = (f32x4)(0.f);

    for (int s = 0; s < 4; ++s) {
        const int kt16 = (hn << 2) + s;
        __syncthreads();
        const char* gW = (const char*)WreB + ((long)kt16 << 15);
        char* lB = (char*)&Blds[0][0][0] + (wc << 10);
        #pragma unroll
        for (int i = 0; i < 8; ++i)
            gload_lds16(gW + (i << 12) + (wc << 10) + (l << 4), lB + (i << 12));
        #pragma unroll
        for (int ss = 0; ss < 2; ++ss) {
            int f4i = tid + (ss << 8);
            int row = f4i >> 3, q = f4i & 7;
            float4 av = *(const float4*)&h0[(c0 + row) * 512 + (hn << 7) + (s << 5) + (q << 2)];
            *reinterpret_cast<unsigned long long*>(&Alds[q >> 1][row][(q & 1) << 2]) = pack4bf(av);
        }
        __syncthreads();

        bf16x8 afr[4], bfr[8];
        #pragma unroll
        for (int m = 0; m < 4; ++m)
            afr[m] = *reinterpret_cast<const bf16x8*>(&Alds[og][(m << 4) + lr][0]);
        #pragma unroll
        for (int n = 0; n < 8; ++n)
            bfr[n] = *reinterpret_cast<const bf16x8*>(&Blds[og][(wc << 7) + (n << 4) + lr][0]);
        #pragma unroll
        for (int m = 0; m < 4; ++m)
            #pragma unroll
            for (int n = 0; n < 8; ++n)
                acc[m][n] = __builtin_amdgcn_mfma_f32_16x16x32_bf16(afr[m], bfr[n], acc[m][n], 0, 0, 0);
    }

    float* Gh = G + (long)hn * (4096L * 512);
    #pragma unroll
    for (int m = 0; m < 4; ++m) {
        const long rb = c0 + (m << 4) + (og << 2);
        #pragma unroll
        for (int n = 0; n < 8; ++n) {
            const int col = (wc << 7) + (n << 4) + lr;
            #pragma unroll
            for (int j = 0; j < 4; ++j)
                Gh[(rb + j) * 512 + col] = acc[m][n][j];
        }
    }
}

// ---------------------------------------------------------------------------
// gemm2: out = B0 @ Wout^T + p.G. A pre-packed bf16 -> pure global_load_lds
// staging for BOTH operands, double-buffered, one barrier per K-step.
// ---------------------------------------------------------------------------
__global__ __launch_bounds__(256, 2) void gemm2(
    const unsigned short* __restrict__ A2, const unsigned short* __restrict__ Wre,
    const float* __restrict__ G, const float* __restrict__ p_buf,
    float* __restrict__ out)
{
    __shared__ alignas(16) unsigned short Blds[2][4][512][8];  // 64 KB
    __shared__ alignas(16) unsigned short Alds[2][4][64][8];   // 8 KB
    __shared__ float pS[64][4];                                // 1 KB
    const int tid = threadIdx.x;
    const int l = tid & 63, wc = tid >> 6;
    const int og = l >> 4, lr = l & 15;
    const long t0 = (long)blockIdx.x * 64;
    const char* gA = (const char*)A2 + (((t0 >> 6) * 16) << 12);

    f32x4 acc[4][8];
    #pragma unroll
    for (int m = 0; m < 4; ++m)
        #pragma unroll
        for (int n = 0; n < 8; ++n) acc[m][n] = (f32x4)(0.f);

    // ---- prologue ----
    {
        const char* gW = (const char*)Wre;
        char* lB = (char*)&Blds[0][0][0][0] + (wc << 10);
        #pragma unroll
        for (int i = 0; i < 8; ++i)
            gload_lds16(gW + (i << 12) + (wc << 10) + (l << 4), lB + (i << 12));
        gload_lds16(gA + (tid << 4), (char*)&Alds[0][0][0][0] + (tid << 4));
    }
    __syncthreads();

    for (int kt16 = 0; kt16 < 16; ++kt16) {
        const int cur = kt16 & 1;
        if (kt16 < 15) {
            const char* gW = (const char*)Wre + ((long)(kt16 + 1) << 15);
            char* lB = (char*)&Blds[cur ^ 1][0][0][0] + (wc << 10);
            #pragma unroll
            for (int i = 0; i < 8; ++i)
                gload_lds16(gW + (i << 12) + (wc << 10) + (l << 4), lB + (i << 12));
            gload_lds16(gA + (((long)(kt16 + 1)) << 12) + (tid << 4),
                        (char*)&Alds[cur ^ 1][0][0][0] + (tid << 4));
        }
        bf16x8 afr[4], bfr[8];
        #pragma unroll
        for (int m = 0; m < 4; ++m)
            afr[m] = *reinterpret_cast<const bf16x8*>(&Alds[cur][og][(m << 4) + lr][0]);
        #pragma unroll
        for (int n = 0; n < 8; ++n)
            bfr[n] = *reinterpret_cast<const bf16x8*>(&Blds[cur][og][(wc << 7) + (n << 4) + lr][0]);
        #pragma unroll
        for (int m = 0; m < 4; ++m)
            #pragma unroll
            for (int n = 0; n < 8; ++n)
                acc[m][n] = __builtin_amdgcn_mfma_f32_16x16x32_bf16(afr[m], bfr[n], acc[m][n], 0, 0, 0);
        if (kt16 < 15) __syncthreads();
    }

    pS[tid >> 2][tid & 3] = p_buf[t0 * 4 + tid];
    __syncthreads();

    #pragma unroll
    for (int m = 0; m < 4; ++m) {
        const long gc = (t0 >> 4) + m;
        #pragma unroll
        for (int n = 0; n < 8; ++n) {
            const int col = (wc << 7) + (n << 4) + lr;
            const float g0 = G[gc * 512 + col];
            const float g1 = G[2097152L + gc * 512 + col];
            const float g2 = G[4194304L + gc * 512 + col];
            const float g3 = G[6291456L + gc * 512 + col];
            #pragma unroll
            for (int j = 0; j < 4; ++j) {
                const int rl = (m << 4) + (og << 2) + j;
                const float add = pS[rl][0]*g0 + pS[rl][1]*g1 + pS[rl][2]*g2 + pS[rl][3]*g3;
                out[(t0 + rl) * 512 + col] = acc[m][n][j] + add;
            }
        }
    }
}

extern "C" void kernel_launch(void* const* d_in, const int* in_sizes, int n_in,
                              void* d_out, int out_size, void* d_ws, size_t ws_size,
                              hipStream_t stream) {
    const float* x       = (const float*)d_in[0];
    const float* h       = (const float*)d_in[1];
    const float* Win     = (const float*)d_in[2];
    const float* gamma   = (const float*)d_in[3];
    const float* beta    = (const float*)d_in[4];
    const float* Wg      = (const float*)d_in[5];
    const float* bg      = (const float*)d_in[6];
    const float* eig_raw = (const float*)d_in[7];
    const float* Wout    = (const float*)d_in[8];

    float* out    = (float*)d_out;                 // xp, then final out
    float* h_last = out + (long)NTOK * DH_;

    float* ws     = (float*)d_ws;
    float* p_buf  = ws;                            //  262144 f
    float* h0_buf = ws + 262144;                   // 2097152 f
    float* B15    = ws + 2359296;                  // 2097152 f
    float* G      = ws + 4456448;                  // 8388608 f
    unsigned short* WreA = (unsigned short*)(ws + 12845056);  // 262144 us
    unsigned short* WreB = WreA + 262144;                     // 262144 us
    unsigned short* A2   = (unsigned short*)(ws + 13107200);  // 33554432 us

    k0_convert<<<1024, 256, 0, stream>>>(Win, Wout, WreA, WreB);
    gemm1<<<NTOK/64, 256, 0, stream>>>(x, WreA, out);
    k_lnA<<<NTOK/16, 256, 0, stream>>>(out, gamma, beta, Wg, bg, eig_raw,
                                       A2, B15, p_buf);
    k3_scan<<<16, 256, 0, stream>>>(p_buf, B15, h, h0_buf, h_last);
    kG<<<256, 256, 0, stream>>>(h0_buf, WreB, G);
    gemm2<<<NTOK/64, 256, 0, stream>>>(A2, WreB, G, p_buf, out);
}